// Round 11
// baseline (230.727 us; speedup 1.0000x reference)
//
#include <hip/hip_runtime.h>

// GCN 2-layer forward (Hu et al. mol-GNN variant) — LDS-sorted coalesced scatter,
// bf16+int8 links, MFMA GEMM, fused agg1+gemm2, GRAPH-COEFFICIENT emb folding.
//
//   dis[n] = 1/sqrt(1 + outdeg(n))
//   out[n] = dis[n]^2*(h_bf16[n]+emb_self) + dn*sum_e dis[s]*q8[s]*sc[s]
//          + dn*(sum_bt cb[bt]*ebond[bt] + sum_bd cd[bd]*edir[bd])   <- 6 coefs/node,
//            layer-independent, computed once at build (emb work off the edge loop).
//
// Measured facts / ledger:
//  - R2: VALU GEMM 59us -> MFMA. R3: LDS-sorted coalesced scatter.
//  - R4..R8: granularity/lane knobs plateau ~221us (R8 = 220.7).
//  - R10: fused agg1+gemm2 = 220.3, absmax bit-identical; Ab round-trip was ~free ->
//    cost is INSIDE the gather loops. agg_gemm: 51us, occ 29%, VALU 29%, LDS bank
//    conflicts 1.05M (embc float4 reads per edge), 16B gather + 17 VALU per edge-lane.
//  - R11 (this): emb folded into 6 per-node graph coefficients (cb0..2, cd0..2),
//    computed in build (LDS float atomics, disv gather is L2-resident 400KB), used by
//    BOTH aggregates. Edge loop: g[s] (4B) + q8 (8B) + 8 FMA, zero LDS. Build splits
//    K2a (degree->disv) / K2b (sort+coef+g1) for the cross-block disv dependency.
// Payload: src(17b) | emb(5b)<<17 | dstLow8(8b)<<22 (30 bits; emb = bt*3+bd in 0..8).

#define THREADS 256
#define NBINS 512    // 256-node buckets, N <= 131072
#define BCAP 4096    // per-bucket edge capacity (mean 2560 @ E=1M,N=100k; sd~51)
#define CHUNK 2048   // edges per scatter block
#define GEMM_SMEM_BYTES (64 * 68 * 4)
// Wv[2048]u32 + SD[2048]u32 + DB[2048]u16 + SDB[2048]u16 + 6*512 ints + 256 ints
#define SC_SMEM (CHUNK * 4 * 2 + CHUNK * 2 * 2 + 6 * NBINS * 4 + 256 * 4)  // 37888

typedef __attribute__((ext_vector_type(8))) short bf16x8;
typedef __attribute__((ext_vector_type(4))) float f32x4;

__device__ __forceinline__ float bflo(unsigned int v) { return __uint_as_float(v << 16); }
__device__ __forceinline__ float bfhi(unsigned int v) { return __uint_as_float(v & 0xFFFF0000u); }
__device__ __forceinline__ unsigned short f2bf(float f) {  // round-to-nearest-even
    unsigned int u = __float_as_uint(f);
    return (unsigned short)((u + 0x7FFFu + ((u >> 16) & 1u)) >> 16);
}
__device__ __forceinline__ int sb(unsigned int w, int j) {  // signed byte j of word
    return (int)(w << (24 - 8 * j)) >> 24;
}

// ---- shared GEMM core pieces -------------------------------------------------
__device__ __forceinline__ void load_bfrags(const float* __restrict__ W, int l15, int lk,
                                            bf16x8 bfr[4][2]) {
#pragma unroll
    for (int n = 0; n < 4; ++n) {
        const float* wp = W + (size_t)(16 * n + l15) * 64 + 8 * lk;
#pragma unroll
        for (int ks = 0; ks < 2; ++ks) {
            float4 u0 = *(const float4*)(wp + 32 * ks);
            float4 u1 = *(const float4*)(wp + 32 * ks + 4);
            bf16x8 bb;
            bb[0] = (short)f2bf(u0.x); bb[1] = (short)f2bf(u0.y);
            bb[2] = (short)f2bf(u0.z); bb[3] = (short)f2bf(u0.w);
            bb[4] = (short)f2bf(u1.x); bb[5] = (short)f2bf(u1.y);
            bb[6] = (short)f2bf(u1.z); bb[7] = (short)f2bf(u1.w);
            bfr[n][ks] = bb;
        }
    }
}

// epilogue: bias+stage smC, then bf16 row + int8 quant row + scale writeout.
// scout[grow] = (dismul ? dismul[grow]*sc : sc)  — sc1 for layer1, g2=dis*sc for layer2.
__device__ __forceinline__ void gemm_epilogue(int tile, f32x4 acc[4],
                                              const float* __restrict__ B, int wave,
                                              int l15, int lk, int t,
                                              unsigned short* __restrict__ Hb,
                                              unsigned char* __restrict__ Hq,
                                              float* __restrict__ scout,
                                              const float* __restrict__ dismul, int N,
                                              float (*smem)[68]) {
#pragma unroll
    for (int n = 0; n < 4; ++n) {
        float bv = B[16 * n + l15];
        int col = 16 * n + l15;
#pragma unroll
        for (int r = 0; r < 4; ++r)
            smem[16 * wave + 4 * lk + r][col] = acc[n][r] + bv;
    }
    __syncthreads();

#pragma unroll
    for (int i = 0; i < 2; ++i) {
        int idx = t + i * THREADS;
        int r = idx >> 3;
        int c8 = (idx & 7) << 3;
        int grow = tile * 64 + r;
        float4 va = *(const float4*)(&smem[r][c8]);
        float4 vb = *(const float4*)(&smem[r][c8 + 4]);
        float v[8] = {va.x, va.y, va.z, va.w, vb.x, vb.y, vb.z, vb.w};
        float m = fabsf(v[0]);
#pragma unroll
        for (int j = 1; j < 8; ++j) m = fmaxf(m, fabsf(v[j]));
        m = fmaxf(m, __shfl_xor(m, 1));  // 8 lanes/row are contiguous
        m = fmaxf(m, __shfl_xor(m, 2));
        m = fmaxf(m, __shfl_xor(m, 4));
        if (grow < N) {
            uint4 o;
            o.x = (unsigned)f2bf(v[0]) | ((unsigned)f2bf(v[1]) << 16);
            o.y = (unsigned)f2bf(v[2]) | ((unsigned)f2bf(v[3]) << 16);
            o.z = (unsigned)f2bf(v[4]) | ((unsigned)f2bf(v[5]) << 16);
            o.w = (unsigned)f2bf(v[6]) | ((unsigned)f2bf(v[7]) << 16);
            *(uint4*)(Hb + (size_t)grow * 64 + c8) = o;
            float inv = m > 0.0f ? 127.0f / m : 0.0f;
            int q[8];
#pragma unroll
            for (int j = 0; j < 8; ++j) q[j] = __float2int_rn(v[j] * inv);
            uint2 qp;
            qp.x = (unsigned)(q[0] & 255) | ((unsigned)(q[1] & 255) << 8) |
                   ((unsigned)(q[2] & 255) << 16) | ((unsigned)(q[3] & 255) << 24);
            qp.y = (unsigned)(q[4] & 255) | ((unsigned)(q[5] & 255) << 8) |
                   ((unsigned)(q[6] & 255) << 16) | ((unsigned)(q[7] & 255) << 24);
            *(uint2*)(Hq + (size_t)grow * 64 + c8) = qp;
            if ((idx & 7) == 0) {
                float sc = m * (1.0f / 127.0f);
                scout[grow] = dismul ? dismul[grow] * sc : sc;
            }
        }
    }
}

// ---- GEMM tile body (MFMA), A from global fp32 (layer 1 riders) ----
__device__ __forceinline__ void gemm64_body(int tile, const float* __restrict__ Xv,
                                            const float* __restrict__ W,
                                            const float* __restrict__ B,
                                            unsigned short* __restrict__ Hb,
                                            unsigned char* __restrict__ Hq,
                                            float* __restrict__ sc1, int N,
                                            float (*smem)[68]) {
    int t = threadIdx.x;
    int lane = t & 63;
    int wave = __builtin_amdgcn_readfirstlane(t >> 6);
    int l15 = lane & 15;
    int lk = lane >> 4;  // k-chunk id 0..3
    int arow = tile * 64 + wave * 16 + l15;

    bf16x8 a0, a1;
    if (arow < N) {
        const float* xp = Xv + (size_t)arow * 64 + 8 * lk;
        float4 v0 = *(const float4*)xp;
        float4 v1 = *(const float4*)(xp + 4);
        float4 v2 = *(const float4*)(xp + 32);
        float4 v3 = *(const float4*)(xp + 36);
        a0[0] = (short)f2bf(v0.x); a0[1] = (short)f2bf(v0.y);
        a0[2] = (short)f2bf(v0.z); a0[3] = (short)f2bf(v0.w);
        a0[4] = (short)f2bf(v1.x); a0[5] = (short)f2bf(v1.y);
        a0[6] = (short)f2bf(v1.z); a0[7] = (short)f2bf(v1.w);
        a1[0] = (short)f2bf(v2.x); a1[1] = (short)f2bf(v2.y);
        a1[2] = (short)f2bf(v2.z); a1[3] = (short)f2bf(v2.w);
        a1[4] = (short)f2bf(v3.x); a1[5] = (short)f2bf(v3.y);
        a1[6] = (short)f2bf(v3.z); a1[7] = (short)f2bf(v3.w);
    } else {
#pragma unroll
        for (int e = 0; e < 8; ++e) { a0[e] = 0; a1[e] = 0; }
    }

    bf16x8 bfr[4][2];
    load_bfrags(W, l15, lk, bfr);

    f32x4 acc[4];
#pragma unroll
    for (int n = 0; n < 4; ++n) {
        f32x4 z = {0.0f, 0.0f, 0.0f, 0.0f};
        z = __builtin_amdgcn_mfma_f32_16x16x32_bf16(a0, bfr[n][0], z, 0, 0, 0);
        acc[n] = __builtin_amdgcn_mfma_f32_16x16x32_bf16(a1, bfr[n][1], z, 0, 0, 0);
    }
    gemm_epilogue(tile, acc, B, wave, l15, lk, t, Hb, Hq, sc1, nullptr, N, smem);
}

// ---- K0: zero the bucket cursors (block 0) + gemm1 tiles (blocks 1..) ----
__global__ __launch_bounds__(THREADS) void zero_gemm_kernel(
    int* __restrict__ gcur, int ncur, const float* __restrict__ X,
    const float* __restrict__ W1, const float* __restrict__ B1,
    unsigned short* __restrict__ Hb, unsigned char* __restrict__ Hq,
    float* __restrict__ sc1, int N, int tile0) {
    __shared__ __align__(16) char sh[GEMM_SMEM_BYTES];
    int b = blockIdx.x;
    if (b == 0) {
        for (int i = threadIdx.x; i < ncur; i += THREADS) gcur[i] = 0;
        return;
    }
    gemm64_body(tile0 + b - 1, X, W1, B1, Hb, Hq, sc1, N, (float(*)[68])sh);
}

// ---- K1: LDS-sorted scatter into 512 bins (unchanged from R8/R10) ----
__global__ __launch_bounds__(THREADS) void scatter_kernel(
    const int* __restrict__ src, const int* __restrict__ dst, const int* __restrict__ attr,
    int* __restrict__ gcurS, int* __restrict__ gcurD, unsigned char* __restrict__ payS,
    unsigned int* __restrict__ payD, int E, int SCB,
    const float* __restrict__ X, const float* __restrict__ W1, const float* __restrict__ B1,
    unsigned short* __restrict__ Hb, unsigned char* __restrict__ Hq,
    float* __restrict__ sc1, int N, int tile0) {
    __shared__ __align__(16) char sh[SC_SMEM];
    int b = blockIdx.x;
    if (b >= SCB) {
        gemm64_body(tile0 + b - SCB, X, W1, B1, Hb, Hq, sc1, N, (float(*)[68])sh);
        return;
    }
    unsigned int* Wv = (unsigned int*)sh;                 // [CHUNK]
    unsigned int* SD = Wv + CHUNK;                        // [CHUNK] dst-sorted words
    unsigned short* DB = (unsigned short*)(SD + CHUNK);   // [CHUNK] dst bin
    unsigned short* SDB = DB + CHUNK;                     // [CHUNK] sorted dst bin
    int* hD = (int*)(SDB + CHUNK);
    int* hS = hD + NBINS;
    int* mapD = hS + NBINS;
    int* mapS = mapD + NBINS;
    int* curD = mapS + NBINS;
    int* curS = curD + NBINS;
    int* scn = curS + NBINS;                              // [256]
    unsigned char* SS = (unsigned char*)Wv;               // reuse after place-D
    unsigned short* SSB = DB;                             // reuse after place-D

    int t = threadIdx.x;
    for (int k = t; k < NBINS; k += THREADS) { hD[k] = 0; hS[k] = 0; }
    __syncthreads();

    int lo = b * CHUNK, hi = min(E, lo + CHUNK);
    int nch = hi - lo;
    const int2* ap = (const int2*)attr;
    for (int li = t; li < nch; li += THREADS) {
        int i = lo + li;
        int sv = src[i], dv = dst[i];
        int2 a = ap[i];
        Wv[li] = (unsigned int)sv | ((unsigned int)(a.x * 3 + a.y) << 17) |
                 ((unsigned int)(dv & 255) << 22);
        DB[li] = (unsigned short)(dv >> 8);
        atomicAdd(&hD[dv >> 8], 1);  // LDS atomic
        atomicAdd(&hS[sv >> 8], 1);  // LDS atomic
    }
    __syncthreads();

    // reserve global ranges (one atomic per touched bin per stream)
    for (int k = t; k < NBINS; k += THREADS) {
        int h = hD[k];
        int r = h ? atomicAdd(&gcurD[k], h) : 0;  // global atomic, low contention
        mapD[k] = k * BCAP + r;
        int h2 = hS[k];
        int r2 = h2 ? atomicAdd(&gcurS[k], h2) : 0;
        mapS[k] = k * BCAP + r2;
    }
    __syncthreads();

    // exclusive scan of hD over 512 bins (2 bins/thread) -> curD (local start), map adj
    scn[t] = hD[2 * t] + hD[2 * t + 1];
    __syncthreads();
    for (int d = 1; d < THREADS; d <<= 1) {
        int a = (t >= d) ? scn[t - d] : 0;
        __syncthreads();
        scn[t] += a;
        __syncthreads();
    }
    {
        int off = t ? scn[t - 1] : 0;
        curD[2 * t] = off;
        curD[2 * t + 1] = off + hD[2 * t];
        mapD[2 * t] -= off;
        mapD[2 * t + 1] -= off + hD[2 * t];
    }
    __syncthreads();
    // same for hS
    scn[t] = hS[2 * t] + hS[2 * t + 1];
    __syncthreads();
    for (int d = 1; d < THREADS; d <<= 1) {
        int a = (t >= d) ? scn[t - d] : 0;
        __syncthreads();
        scn[t] += a;
        __syncthreads();
    }
    {
        int off = t ? scn[t - 1] : 0;
        curS[2 * t] = off;
        curS[2 * t + 1] = off + hS[2 * t];
        mapS[2 * t] -= off;
        mapS[2 * t + 1] -= off + hS[2 * t];
    }
    __syncthreads();

    // place by dst-bin (consumes Wv/DB into SD/SDB)
    for (int li = t; li < nch; li += THREADS) {
        int k = DB[li];
        int p = atomicAdd(&curD[k], 1);  // LDS atomic
        SD[p] = Wv[li];
        SDB[p] = (unsigned short)k;
    }
    __syncthreads();

    // place by src-bin (sources from SD; reuses Wv region as SS, DB as SSB)
    for (int li = t; li < nch; li += THREADS) {
        int val = (int)(SD[li] & 0x1FFFFu);
        int k = val >> 8;
        int p = atomicAdd(&curS[k], 1);  // LDS atomic
        SS[p] = (unsigned char)(val & 255);
        SSB[p] = (unsigned short)k;
    }
    __syncthreads();

    // linear coalesced writeout
    for (int li = t; li < nch; li += THREADS) {
        payD[mapD[SDB[li]] + li] = SD[li];
        payS[mapS[SSB[li]] + li] = SS[li];
    }
}

// ---- K2a: out-degree histogram per 256-node bucket -> disv ----
__global__ __launch_bounds__(THREADS) void build_deg_kernel(
    const unsigned char* __restrict__ payS, const int* __restrict__ gcurS,
    float* __restrict__ disv, int N) {
    __shared__ int cnt[256];
    int t = threadIdx.x;
    int k = blockIdx.x;
    cnt[t] = 0;
    __syncthreads();
    int n = gcurS[k], off = k * BCAP;
    for (int i = t; i < n; i += THREADS) atomicAdd(&cnt[payS[off + i]], 1);  // LDS atomic
    __syncthreads();
    int node = k * 256 + t;
    if (node < N) disv[node] = 1.0f / sqrtf(1.0f + (float)cnt[t]);
}

// ---- K2b: per bucket: 256-bin counting sort -> sorted + rc, PLUS graph coefficients
// coef[node] = {cb0,cb1,cb2,cd0,cd1,cd2,0,0} (Σ dis[src] per bond-type / bond-dir),
// layer-independent; and g1[node] = disv*sc1. disv gather is L2-resident (400 KB).
__global__ __launch_bounds__(THREADS) void build_sort_kernel(
    const unsigned int* __restrict__ payD, const int* __restrict__ gcurD,
    unsigned int* __restrict__ sorted, int2* __restrict__ rc,
    const float* __restrict__ disv, const float* __restrict__ sc1,
    float* __restrict__ coefv, float* __restrict__ g1, int N) {
    __shared__ int cnt[256];
    __shared__ int cur[256];
    __shared__ int s[THREADS];
    __shared__ float coefL[256][8];
    int t = threadIdx.x;
    int k = blockIdx.x;
    cnt[t] = 0;
#pragma unroll
    for (int j = 0; j < 8; ++j) coefL[t][j] = 0.0f;
    __syncthreads();
    int ecnt = gcurD[k], eoff = k * BCAP;
    for (int i = t; i < ecnt; i += THREADS)
        atomicAdd(&cnt[(payD[eoff + i] >> 22) & 255], 1);  // LDS atomic
    __syncthreads();
    int v = cnt[t];
    s[t] = v;
    __syncthreads();
    for (int d = 1; d < THREADS; d <<= 1) {
        int a = (t >= d) ? s[t - d] : 0;
        __syncthreads();
        s[t] += a;
        __syncthreads();
    }
    int excl = s[t] - v;
    int node = k * 256 + t;
    if (node < N) rc[node] = make_int2(eoff + excl, v);
    cur[t] = excl;
    __syncthreads();
    for (int i = t; i < ecnt; i += THREADS) {
        unsigned int u = payD[eoff + i];
        int d8 = (u >> 22) & 255;
        int p = atomicAdd(&cur[d8], 1);     // LDS atomic
        sorted[eoff + p] = u & 0x3FFFFFu;   // keep src | emb<<17
        int s0 = u & 0x1FFFF;
        int e = (u >> 17) & 31;             // bt*3+bd, 0..8
        int bt = (e >= 6) ? 2 : ((e >= 3) ? 1 : 0);
        int bd = e - 3 * bt;
        float dv = disv[s0];                // L2-resident gather
        atomicAdd(&coefL[d8][bt], dv);      // LDS float atomic
        atomicAdd(&coefL[d8][4 + bd], dv);  // LDS float atomic
    }
    __syncthreads();
    if (node < N) {
        float4 c0 = make_float4(coefL[t][0], coefL[t][1], coefL[t][2], coefL[t][4]);
        float4 c1 = make_float4(coefL[t][5], coefL[t][6], 0.0f, 0.0f);
        *(float4*)(coefv + 8 * (size_t)node) = c0;      // cb0,cb1,cb2,cd0
        *(float4*)(coefv + 8 * (size_t)node + 4) = c1;  // cd1,cd2,pad,pad
        g1[node] = disv[node] * sc1[node];
    }
}

// ---- lean aggregate: per edge only g[s] (4B) + q8 (8B) + 8 FMA; emb via 6 coefs ----
// et rows: 0-2 = ebond[0..2], 3-5 = edir[0..2], 6 = self emb (ebond[4]+edir[0]).
__device__ __forceinline__ void edge_acc(unsigned int u, float dn,
                                         const float* __restrict__ g,
                                         const unsigned char* __restrict__ Hq, int c,
                                         float acc[8]) {
    int s0 = u & 0x1FFFF;
    float w = dn * g[s0];
    uint2 q = *(const uint2*)(Hq + (size_t)s0 * 64 + c);
    acc[0] = fmaf(w, (float)sb(q.x, 0), acc[0]);
    acc[1] = fmaf(w, (float)sb(q.x, 1), acc[1]);
    acc[2] = fmaf(w, (float)sb(q.x, 2), acc[2]);
    acc[3] = fmaf(w, (float)sb(q.x, 3), acc[3]);
    acc[4] = fmaf(w, (float)sb(q.y, 0), acc[4]);
    acc[5] = fmaf(w, (float)sb(q.y, 1), acc[5]);
    acc[6] = fmaf(w, (float)sb(q.y, 2), acc[6]);
    acc[7] = fmaf(w, (float)sb(q.y, 3), acc[7]);
}

__device__ __forceinline__ void agg_node(int n, int c, const unsigned short* __restrict__ Hb,
                                         const unsigned char* __restrict__ Hq,
                                         const float* __restrict__ disv,
                                         const float* __restrict__ g,
                                         const float* __restrict__ coefv,
                                         const int2* __restrict__ rc,
                                         const unsigned int* __restrict__ entries,
                                         const float (*et)[64], float o[8]) {
    float dn = disv[n];
    uint4 hv = *(const uint4*)(Hb + (size_t)n * 64 + c);
    float4 ea = *(const float4*)(&et[6][c]);
    float4 eb = *(const float4*)(&et[6][c + 4]);
    float nrm = dn * dn;
    float accA[8], accB[8];
    accA[0] = nrm * (bflo(hv.x) + ea.x);
    accA[1] = nrm * (bfhi(hv.x) + ea.y);
    accA[2] = nrm * (bflo(hv.y) + ea.z);
    accA[3] = nrm * (bfhi(hv.y) + ea.w);
    accA[4] = nrm * (bflo(hv.z) + eb.x);
    accA[5] = nrm * (bfhi(hv.z) + eb.y);
    accA[6] = nrm * (bflo(hv.w) + eb.z);
    accA[7] = nrm * (bfhi(hv.w) + eb.w);
#pragma unroll
    for (int j = 0; j < 8; ++j) accB[j] = 0.0f;

    int2 pc = rc[n];
    int p = pc.x;
    int end = p + pc.y;
    for (; p + 3 < end; p += 4) {
        unsigned int u0 = entries[p];
        unsigned int u1 = entries[p + 1];
        unsigned int u2 = entries[p + 2];
        unsigned int u3 = entries[p + 3];
        edge_acc(u0, dn, g, Hq, c, accA);
        edge_acc(u1, dn, g, Hq, c, accB);
        edge_acc(u2, dn, g, Hq, c, accA);
        edge_acc(u3, dn, g, Hq, c, accB);
    }
    for (; p < end; ++p) edge_acc(entries[p], dn, g, Hq, c, accA);

    // emb part: dn * (cb·ebond + cd·edir), 6 coefs (lanes of a node share -> merged)
    float4 c0 = *(const float4*)(coefv + 8 * (size_t)n);      // cb0,cb1,cb2,cd0
    float4 c1 = *(const float4*)(coefv + 8 * (size_t)n + 4);  // cd1,cd2,-,-
#pragma unroll
    for (int j = 0; j < 8; ++j) {
        float e = c0.x * et[0][c + j];
        e = fmaf(c0.y, et[1][c + j], e);
        e = fmaf(c0.z, et[2][c + j], e);
        e = fmaf(c0.w, et[3][c + j], e);
        e = fmaf(c1.x, et[4][c + j], e);
        e = fmaf(c1.y, et[5][c + j], e);
        o[j] = fmaf(dn, e, accA[j] + accB[j]);
    }
}

// emb-table fill: 7 rows x 64
__device__ __forceinline__ void fill_et(float (*et)[64], const float* __restrict__ ebond,
                                        const float* __restrict__ edir) {
    int t = threadIdx.x;
    for (int i = t; i < 7 * 64; i += THREADS) {
        int row = i >> 6, c = i & 63;
        float v;
        if (row < 3) v = ebond[row * 64 + c];
        else if (row < 6) v = edir[(row - 3) * 64 + c];
        else v = ebond[4 * 64 + c] + edir[c];  // self: bt=4, bd=0
        et[row][c] = v;
    }
}

// ---- K3 FUSED: lean aggregate layer 1 (ReLU, bf16) -> LDS tile -> MFMA gemm2 ----
__global__ __launch_bounds__(THREADS) void agg_gemm_kernel(
    const unsigned short* __restrict__ Hb1, const unsigned char* __restrict__ Hq1,
    const float* __restrict__ disv, const float* __restrict__ g1,
    const float* __restrict__ coefv, const float* __restrict__ ebond,
    const float* __restrict__ edir, const int2* __restrict__ rc,
    const unsigned int* __restrict__ entries, const float* __restrict__ W,
    const float* __restrict__ B, unsigned short* __restrict__ Hb2,
    unsigned char* __restrict__ Hq2, float* __restrict__ g2, int N) {
    __shared__ float et[7][64];
    __shared__ __align__(16) unsigned short smA[64][72];  // bf16 A-tile, stride 72
    __shared__ __align__(16) float smC[64][68];           // epilogue staging
    int t = threadIdx.x;
    fill_et(et, ebond, edir);
    __syncthreads();

    int tile = blockIdx.x;
    const float(*ec)[64] = (const float(*)[64])et;
#pragma unroll 1
    for (int r = 0; r < 2; ++r) {
        int ln = r * 32 + (t >> 3);  // local row 0..63
        int n = tile * 64 + ln;
        int c = (t & 7) << 3;
        uint4 ov = make_uint4(0u, 0u, 0u, 0u);
        if (n < N) {
            float o[8];
            agg_node(n, c, Hb1, Hq1, disv, g1, coefv, rc, entries, ec, o);
            ov.x = (unsigned)f2bf(fmaxf(o[0], 0.0f)) | ((unsigned)f2bf(fmaxf(o[1], 0.0f)) << 16);
            ov.y = (unsigned)f2bf(fmaxf(o[2], 0.0f)) | ((unsigned)f2bf(fmaxf(o[3], 0.0f)) << 16);
            ov.z = (unsigned)f2bf(fmaxf(o[4], 0.0f)) | ((unsigned)f2bf(fmaxf(o[5], 0.0f)) << 16);
            ov.w = (unsigned)f2bf(fmaxf(o[6], 0.0f)) | ((unsigned)f2bf(fmaxf(o[7], 0.0f)) << 16);
        }
        *(uint4*)(&smA[ln][c]) = ov;  // (ln*72 + c)*2 bytes: 16B-aligned
    }
    __syncthreads();

    // gemm2 from the LDS A-tile
    int lane = t & 63;
    int wave = __builtin_amdgcn_readfirstlane(t >> 6);
    int l15 = lane & 15;
    int lk = lane >> 4;
    int lrow = wave * 16 + l15;
    bf16x8 a0 = *(const bf16x8*)(&smA[lrow][8 * lk]);
    bf16x8 a1 = *(const bf16x8*)(&smA[lrow][8 * lk + 32]);

    bf16x8 bfr[4][2];
    load_bfrags(W, l15, lk, bfr);

    f32x4 acc[4];
#pragma unroll
    for (int n = 0; n < 4; ++n) {
        f32x4 z = {0.0f, 0.0f, 0.0f, 0.0f};
        z = __builtin_amdgcn_mfma_f32_16x16x32_bf16(a0, bfr[n][0], z, 0, 0, 0);
        acc[n] = __builtin_amdgcn_mfma_f32_16x16x32_bf16(a1, bfr[n][1], z, 0, 0, 0);
    }
    gemm_epilogue(tile, acc, B, wave, l15, lk, t, Hb2, Hq2, g2, disv, N, smC);
}

// ---- K4: standalone lean aggregate (layer 2 -> fp32 out) ----
__global__ __launch_bounds__(THREADS) void aggregate_kernel(
    const unsigned short* __restrict__ Hb, const unsigned char* __restrict__ Hq,
    const float* __restrict__ disv, const float* __restrict__ g,
    const float* __restrict__ coefv, const float* __restrict__ ebond,
    const float* __restrict__ edir, const int2* __restrict__ rc,
    const unsigned int* __restrict__ entries, float* __restrict__ out, int N) {
    __shared__ float et[7][64];
    int t = threadIdx.x;
    fill_et(et, ebond, edir);
    __syncthreads();

    int n = blockIdx.x * 32 + (t >> 3);
    if (n >= N) return;
    int c = (t & 7) << 3;
    float o[8];
    agg_node(n, c, Hb, Hq, disv, g, coefv, rc, entries, (const float(*)[64])et, o);
    *(float4*)(out + (size_t)n * 64 + c) = make_float4(o[0], o[1], o[2], o[3]);
    *(float4*)(out + (size_t)n * 64 + c + 4) = make_float4(o[4], o[5], o[6], o[7]);
}

extern "C" void kernel_launch(void* const* d_in, const int* in_sizes, int n_in,
                              void* d_out, int out_size, void* d_ws, size_t ws_size,
                              hipStream_t stream) {
    const float* x      = (const float*)d_in[0];
    const int*   eidx   = (const int*)d_in[1];
    const int*   eattr  = (const int*)d_in[2];
    const float* W1     = (const float*)d_in[3];
    const float* b1     = (const float*)d_in[4];
    const float* ebond1 = (const float*)d_in[5];
    const float* edir1  = (const float*)d_in[6];
    const float* W2     = (const float*)d_in[7];
    const float* b2     = (const float*)d_in[8];
    const float* ebond2 = (const float*)d_in[9];
    const float* edir2  = (const float*)d_in[10];

    const int N = in_sizes[0] / 64;
    const int E = in_sizes[1] / 2;
    const int* src = eidx;
    const int* dst = eidx + E;
    float* out = (float*)d_out;
    const int NB2 = (N + 255) >> 8;         // 256-node buckets
    const int SCB = (E + CHUNK - 1) / CHUNK;

    // Workspace (~62 MB of 256 MiB)
    char* w = (char*)d_ws;
    size_t Na = ((size_t)N * 4 + 255) & ~(size_t)255;
    float* disv    = (float*)w;            w += Na;       // 1/sqrt(1+deg)
    float* sc1     = (float*)w;            w += Na;       // layer1 quant scale
    float* g1      = (float*)w;            w += Na;       // dis*sc1
    float* g2      = (float*)w;            w += Na;       // dis*sc2
    float* coefv   = (float*)w;            w += 8 * Na;   // 6 graph coefs + pad, 32B/node
    int2*  rc      = (int2*)w;             w += 2 * Na;   // {row_ptr, cnt}
    int*   gcur    = (int*)w;              w += 2 * NBINS * 4;
    unsigned int* payD   = (unsigned int*)w;   w += (size_t)NBINS * BCAP * 4;   // 8 MB
    unsigned int* sorted = (unsigned int*)w;   w += (size_t)NBINS * BCAP * 4;   // 8 MB
    unsigned char* payS  = (unsigned char*)w;  w += (size_t)NBINS * BCAP;       // 2 MB
    unsigned short* Hb1  = (unsigned short*)w; w += (size_t)N * 64 * 2;         // 12.8 MB
    unsigned char*  Hq1  = (unsigned char*)w;  w += ((size_t)N * 64 + 255) & ~(size_t)255;
    unsigned short* Hb2  = (unsigned short*)w; w += (size_t)N * 64 * 2;         // 12.8 MB
    unsigned char*  Hq2  = (unsigned char*)w;  w += ((size_t)N * 64 + 255) & ~(size_t)255;
    int* gcurS = gcur;
    int* gcurD = gcur + NBINS;

    const int gT   = (N + 63) / 64;   // gemm/fused tiles
    const int gN32 = (N + 31) / 32;   // aggregate: 32 nodes/block

    // all gemm1 tiles ride in K0+K1 (gemm1 depends only on x; must be done before K3)
    const int t0 = min(gT, 512);
    const int t1 = gT - t0;

    zero_gemm_kernel<<<1 + t0, THREADS, 0, stream>>>(gcur, 2 * NBINS, x, W1, b1, Hb1, Hq1,
                                                     sc1, N, 0);
    scatter_kernel<<<SCB + t1, THREADS, 0, stream>>>(src, dst, eattr, gcurS, gcurD, payS,
                                                     payD, E, SCB, x, W1, b1, Hb1, Hq1,
                                                     sc1, N, t0);
    build_deg_kernel<<<NB2, THREADS, 0, stream>>>(payS, gcurS, disv, N);
    build_sort_kernel<<<NB2, THREADS, 0, stream>>>(payD, gcurD, sorted, rc, disv, sc1,
                                                   coefv, g1, N);

    // fused: lean aggregate layer 1 (ReLU,bf16 in LDS) -> gemm2 -> Hb2/Hq2/g2
    agg_gemm_kernel<<<gT, THREADS, 0, stream>>>(Hb1, Hq1, disv, g1, coefv, ebond1, edir1,
                                                rc, sorted, W2, b2, Hb2, Hq2, g2, N);

    // layer 2 lean aggregate -> fp32 out
    aggregate_kernel<<<gN32, THREADS, 0, stream>>>(Hb2, Hq2, disv, g2, coefv, ebond2,
                                                   edir2, rc, sorted, out, N);
}

// Round 12
// 222.606 us; speedup vs baseline: 1.0365x; 1.0365x over previous
//
#include <hip/hip_runtime.h>

// GCN 2-layer forward (Hu et al. mol-GNN variant) — LDS-sorted coalesced scatter,
// bf16 + 128-B int8 RECORD links ({q row, dis, sc} in one cache line), MFMA GEMM,
// fused agg1+gemm2.
//
//   dis[n] = 1/sqrt(1 + outdeg(n))
//   out[n] = dis[n]^2*(h_bf16[n]+emb_self) + sum_e dis[s]*dis[n]*(q8[s]*sc[s]+emb_e)
//
// Measured facts / ledger:
//  - R2: VALU GEMM 59us -> MFMA. R3: LDS-sorted coalesced scatter. R8 = 220.7 anchor.
//  - R10: fused agg1+gemm2 = 220.3 (Ab round-trip ~free); agg_gemm 51us, occ 29%,
//    VALU 29% -> cost is the per-edge random gathers.
//  - R11 REGRESSED (230.7): coef-folded emb (leaner VALU, conflicts 1.05M->150K) but
//    agg_gemm +2.6us -> edge loop is REQUEST-bound, not VALU/LDS-bound. Reverted.
//  - R12 (this): R10 + record merge. Quant record = 128-B line {64x int8, float dis,
//    float sc}; the edge loop's second random stream (dsc gather) becomes a same-line
//    L1 hit -> per-edge random line requests 2 -> 1. The Hq line itself is compulsory
//    (random graph, line granularity). Math identical to R10 -> absmax bit-identical.
//  - Record fill order: sc @+68 by gemm1 epilogue (K0/K1); dis @+64 by build phase A
//    (K2); different words, no race. Layer-2 record {dis,sc} written by fused epilogue.
// Payload: src(17b) | emb(5b)<<17 | dstLow8(8b)<<22 (30 bits).

#define THREADS 256
#define NBINS 512    // 256-node buckets, N <= 131072
#define BCAP 4096    // per-bucket edge capacity (mean 2560 @ E=1M,N=100k; sd~51)
#define CHUNK 2048   // edges per scatter block
#define GEMM_SMEM_BYTES (64 * 68 * 4)
// Wv[2048]u32 + SD[2048]u32 + DB[2048]u16 + SDB[2048]u16 + 6*512 ints + 256 ints
#define SC_SMEM (CHUNK * 4 * 2 + CHUNK * 2 * 2 + 6 * NBINS * 4 + 256 * 4)  // 37888

typedef __attribute__((ext_vector_type(8))) short bf16x8;
typedef __attribute__((ext_vector_type(4))) float f32x4;

__device__ __forceinline__ float bflo(unsigned int v) { return __uint_as_float(v << 16); }
__device__ __forceinline__ float bfhi(unsigned int v) { return __uint_as_float(v & 0xFFFF0000u); }
__device__ __forceinline__ unsigned short f2bf(float f) {  // round-to-nearest-even
    unsigned int u = __float_as_uint(f);
    return (unsigned short)((u + 0x7FFFu + ((u >> 16) & 1u)) >> 16);
}
__device__ __forceinline__ int sb(unsigned int w, int j) {  // signed byte j of word
    return (int)(w << (24 - 8 * j)) >> 24;
}

// ---- shared GEMM core pieces -------------------------------------------------
__device__ __forceinline__ void load_bfrags(const float* __restrict__ W, int l15, int lk,
                                            bf16x8 bfr[4][2]) {
#pragma unroll
    for (int n = 0; n < 4; ++n) {
        const float* wp = W + (size_t)(16 * n + l15) * 64 + 8 * lk;
#pragma unroll
        for (int ks = 0; ks < 2; ++ks) {
            float4 u0 = *(const float4*)(wp + 32 * ks);
            float4 u1 = *(const float4*)(wp + 32 * ks + 4);
            bf16x8 bb;
            bb[0] = (short)f2bf(u0.x); bb[1] = (short)f2bf(u0.y);
            bb[2] = (short)f2bf(u0.z); bb[3] = (short)f2bf(u0.w);
            bb[4] = (short)f2bf(u1.x); bb[5] = (short)f2bf(u1.y);
            bb[6] = (short)f2bf(u1.z); bb[7] = (short)f2bf(u1.w);
            bfr[n][ks] = bb;
        }
    }
}

// epilogue: bias+stage smC, then bf16 row + int8 record writeout.
// Record @ Hqr + grow*128: bytes 0..63 = q row; +64 = dis; +68 = sc.
// dismul == nullptr (layer 1): write only sc @+68 (dis filled later by build phase A).
// dismul != nullptr (layer 2): write {dis, sc} @+64 together.
__device__ __forceinline__ void gemm_epilogue(int tile, f32x4 acc[4],
                                              const float* __restrict__ B, int wave,
                                              int l15, int lk, int t,
                                              unsigned short* __restrict__ Hb,
                                              unsigned char* __restrict__ Hqr,
                                              const float* __restrict__ dismul, int N,
                                              float (*smem)[68]) {
#pragma unroll
    for (int n = 0; n < 4; ++n) {
        float bv = B[16 * n + l15];
        int col = 16 * n + l15;
#pragma unroll
        for (int r = 0; r < 4; ++r)
            smem[16 * wave + 4 * lk + r][col] = acc[n][r] + bv;
    }
    __syncthreads();

#pragma unroll
    for (int i = 0; i < 2; ++i) {
        int idx = t + i * THREADS;
        int r = idx >> 3;
        int c8 = (idx & 7) << 3;
        int grow = tile * 64 + r;
        float4 va = *(const float4*)(&smem[r][c8]);
        float4 vb = *(const float4*)(&smem[r][c8 + 4]);
        float v[8] = {va.x, va.y, va.z, va.w, vb.x, vb.y, vb.z, vb.w};
        float m = fabsf(v[0]);
#pragma unroll
        for (int j = 1; j < 8; ++j) m = fmaxf(m, fabsf(v[j]));
        m = fmaxf(m, __shfl_xor(m, 1));  // 8 lanes/row are contiguous
        m = fmaxf(m, __shfl_xor(m, 2));
        m = fmaxf(m, __shfl_xor(m, 4));
        if (grow < N) {
            uint4 o;
            o.x = (unsigned)f2bf(v[0]) | ((unsigned)f2bf(v[1]) << 16);
            o.y = (unsigned)f2bf(v[2]) | ((unsigned)f2bf(v[3]) << 16);
            o.z = (unsigned)f2bf(v[4]) | ((unsigned)f2bf(v[5]) << 16);
            o.w = (unsigned)f2bf(v[6]) | ((unsigned)f2bf(v[7]) << 16);
            *(uint4*)(Hb + (size_t)grow * 64 + c8) = o;
            float inv = m > 0.0f ? 127.0f / m : 0.0f;
            int q[8];
#pragma unroll
            for (int j = 0; j < 8; ++j) q[j] = __float2int_rn(v[j] * inv);
            uint2 qp;
            qp.x = (unsigned)(q[0] & 255) | ((unsigned)(q[1] & 255) << 8) |
                   ((unsigned)(q[2] & 255) << 16) | ((unsigned)(q[3] & 255) << 24);
            qp.y = (unsigned)(q[4] & 255) | ((unsigned)(q[5] & 255) << 8) |
                   ((unsigned)(q[6] & 255) << 16) | ((unsigned)(q[7] & 255) << 24);
            unsigned char* rec = Hqr + (size_t)grow * 128;
            *(uint2*)(rec + c8) = qp;
            if ((idx & 7) == 0) {
                float sc = m * (1.0f / 127.0f);
                if (dismul) *(float2*)(rec + 64) = make_float2(dismul[grow], sc);
                else *(float*)(rec + 68) = sc;
            }
        }
    }
}

// ---- GEMM tile body (MFMA), A from global fp32 (layer 1 riders) ----
__device__ __forceinline__ void gemm64_body(int tile, const float* __restrict__ Xv,
                                            const float* __restrict__ W,
                                            const float* __restrict__ B,
                                            unsigned short* __restrict__ Hb,
                                            unsigned char* __restrict__ Hqr, int N,
                                            float (*smem)[68]) {
    int t = threadIdx.x;
    int lane = t & 63;
    int wave = __builtin_amdgcn_readfirstlane(t >> 6);
    int l15 = lane & 15;
    int lk = lane >> 4;  // k-chunk id 0..3
    int arow = tile * 64 + wave * 16 + l15;

    bf16x8 a0, a1;
    if (arow < N) {
        const float* xp = Xv + (size_t)arow * 64 + 8 * lk;
        float4 v0 = *(const float4*)xp;
        float4 v1 = *(const float4*)(xp + 4);
        float4 v2 = *(const float4*)(xp + 32);
        float4 v3 = *(const float4*)(xp + 36);
        a0[0] = (short)f2bf(v0.x); a0[1] = (short)f2bf(v0.y);
        a0[2] = (short)f2bf(v0.z); a0[3] = (short)f2bf(v0.w);
        a0[4] = (short)f2bf(v1.x); a0[5] = (short)f2bf(v1.y);
        a0[6] = (short)f2bf(v1.z); a0[7] = (short)f2bf(v1.w);
        a1[0] = (short)f2bf(v2.x); a1[1] = (short)f2bf(v2.y);
        a1[2] = (short)f2bf(v2.z); a1[3] = (short)f2bf(v2.w);
        a1[4] = (short)f2bf(v3.x); a1[5] = (short)f2bf(v3.y);
        a1[6] = (short)f2bf(v3.z); a1[7] = (short)f2bf(v3.w);
    } else {
#pragma unroll
        for (int e = 0; e < 8; ++e) { a0[e] = 0; a1[e] = 0; }
    }

    bf16x8 bfr[4][2];
    load_bfrags(W, l15, lk, bfr);

    f32x4 acc[4];
#pragma unroll
    for (int n = 0; n < 4; ++n) {
        f32x4 z = {0.0f, 0.0f, 0.0f, 0.0f};
        z = __builtin_amdgcn_mfma_f32_16x16x32_bf16(a0, bfr[n][0], z, 0, 0, 0);
        acc[n] = __builtin_amdgcn_mfma_f32_16x16x32_bf16(a1, bfr[n][1], z, 0, 0, 0);
    }
    gemm_epilogue(tile, acc, B, wave, l15, lk, t, Hb, Hqr, nullptr, N, smem);
}

// ---- K0: zero the bucket cursors (block 0) + gemm1 tiles (blocks 1..) ----
__global__ __launch_bounds__(THREADS) void zero_gemm_kernel(
    int* __restrict__ gcur, int ncur, const float* __restrict__ X,
    const float* __restrict__ W1, const float* __restrict__ B1,
    unsigned short* __restrict__ Hb, unsigned char* __restrict__ Hqr, int N, int tile0) {
    __shared__ __align__(16) char sh[GEMM_SMEM_BYTES];
    int b = blockIdx.x;
    if (b == 0) {
        for (int i = threadIdx.x; i < ncur; i += THREADS) gcur[i] = 0;
        return;
    }
    gemm64_body(tile0 + b - 1, X, W1, B1, Hb, Hqr, N, (float(*)[68])sh);
}

// ---- K1: LDS-sorted scatter into 512 bins (unchanged from R8/R10) ----
__global__ __launch_bounds__(THREADS) void scatter_kernel(
    const int* __restrict__ src, const int* __restrict__ dst, const int* __restrict__ attr,
    int* __restrict__ gcurS, int* __restrict__ gcurD, unsigned char* __restrict__ payS,
    unsigned int* __restrict__ payD, int E, int SCB,
    const float* __restrict__ X, const float* __restrict__ W1, const float* __restrict__ B1,
    unsigned short* __restrict__ Hb, unsigned char* __restrict__ Hqr, int N, int tile0) {
    __shared__ __align__(16) char sh[SC_SMEM];
    int b = blockIdx.x;
    if (b >= SCB) {
        gemm64_body(tile0 + b - SCB, X, W1, B1, Hb, Hqr, N, (float(*)[68])sh);
        return;
    }
    unsigned int* Wv = (unsigned int*)sh;                 // [CHUNK]
    unsigned int* SD = Wv + CHUNK;                        // [CHUNK] dst-sorted words
    unsigned short* DB = (unsigned short*)(SD + CHUNK);   // [CHUNK] dst bin
    unsigned short* SDB = DB + CHUNK;                     // [CHUNK] sorted dst bin
    int* hD = (int*)(SDB + CHUNK);
    int* hS = hD + NBINS;
    int* mapD = hS + NBINS;
    int* mapS = mapD + NBINS;
    int* curD = mapS + NBINS;
    int* curS = curD + NBINS;
    int* scn = curS + NBINS;                              // [256]
    unsigned char* SS = (unsigned char*)Wv;               // reuse after place-D
    unsigned short* SSB = DB;                             // reuse after place-D

    int t = threadIdx.x;
    for (int k = t; k < NBINS; k += THREADS) { hD[k] = 0; hS[k] = 0; }
    __syncthreads();

    int lo = b * CHUNK, hi = min(E, lo + CHUNK);
    int nch = hi - lo;
    const int2* ap = (const int2*)attr;
    for (int li = t; li < nch; li += THREADS) {
        int i = lo + li;
        int sv = src[i], dv = dst[i];
        int2 a = ap[i];
        Wv[li] = (unsigned int)sv | ((unsigned int)(a.x * 3 + a.y) << 17) |
                 ((unsigned int)(dv & 255) << 22);
        DB[li] = (unsigned short)(dv >> 8);
        atomicAdd(&hD[dv >> 8], 1);  // LDS atomic
        atomicAdd(&hS[sv >> 8], 1);  // LDS atomic
    }
    __syncthreads();

    // reserve global ranges (one atomic per touched bin per stream)
    for (int k = t; k < NBINS; k += THREADS) {
        int h = hD[k];
        int r = h ? atomicAdd(&gcurD[k], h) : 0;  // global atomic, low contention
        mapD[k] = k * BCAP + r;
        int h2 = hS[k];
        int r2 = h2 ? atomicAdd(&gcurS[k], h2) : 0;
        mapS[k] = k * BCAP + r2;
    }
    __syncthreads();

    // exclusive scan of hD over 512 bins (2 bins/thread) -> curD (local start), map adj
    scn[t] = hD[2 * t] + hD[2 * t + 1];
    __syncthreads();
    for (int d = 1; d < THREADS; d <<= 1) {
        int a = (t >= d) ? scn[t - d] : 0;
        __syncthreads();
        scn[t] += a;
        __syncthreads();
    }
    {
        int off = t ? scn[t - 1] : 0;
        curD[2 * t] = off;
        curD[2 * t + 1] = off + hD[2 * t];
        mapD[2 * t] -= off;
        mapD[2 * t + 1] -= off + hD[2 * t];
    }
    __syncthreads();
    // same for hS
    scn[t] = hS[2 * t] + hS[2 * t + 1];
    __syncthreads();
    for (int d = 1; d < THREADS; d <<= 1) {
        int a = (t >= d) ? scn[t - d] : 0;
        __syncthreads();
        scn[t] += a;
        __syncthreads();
    }
    {
        int off = t ? scn[t - 1] : 0;
        curS[2 * t] = off;
        curS[2 * t + 1] = off + hS[2 * t];
        mapS[2 * t] -= off;
        mapS[2 * t + 1] -= off + hS[2 * t];
    }
    __syncthreads();

    // place by dst-bin (consumes Wv/DB into SD/SDB)
    for (int li = t; li < nch; li += THREADS) {
        int k = DB[li];
        int p = atomicAdd(&curD[k], 1);  // LDS atomic
        SD[p] = Wv[li];
        SDB[p] = (unsigned short)k;
    }
    __syncthreads();

    // place by src-bin (sources from SD; reuses Wv region as SS, DB as SSB)
    for (int li = t; li < nch; li += THREADS) {
        int val = (int)(SD[li] & 0x1FFFFu);
        int k = val >> 8;
        int p = atomicAdd(&curS[k], 1);  // LDS atomic
        SS[p] = (unsigned char)(val & 255);
        SSB[p] = (unsigned short)k;
    }
    __syncthreads();

    // linear coalesced writeout
    for (int li = t; li < nch; li += THREADS) {
        payD[mapD[SDB[li]] + li] = SD[li];
        payS[mapS[SSB[li]] + li] = SS[li];
    }
}

// ---- K2: build at 256-node buckets. Blocks [0,NB2): out-degree -> disv AND the
// layer-1 record's dis word (@+64; sc @+68 was written by gemm1 — different word, no
// race). Blocks [NB2,2*NB2): 256-bin counting sort -> sorted + rc{row_ptr,cnt}.
__global__ __launch_bounds__(THREADS) void build_kernel(
    const unsigned char* __restrict__ payS, const unsigned int* __restrict__ payD,
    const int* __restrict__ gcurS, const int* __restrict__ gcurD,
    unsigned int* __restrict__ sorted, int2* __restrict__ rc,
    float* __restrict__ disv, unsigned char* __restrict__ Hqr1, int NB2, int N) {
    __shared__ int cnt[256];
    __shared__ int cur[256];
    __shared__ int s[THREADS];
    int t = threadIdx.x;
    int b = blockIdx.x;
    if (b < NB2) {
        // phase A: out-degree for bucket b
        int k = b;
        cnt[t] = 0;
        __syncthreads();
        int n = gcurS[k], off = k * BCAP;
        for (int i = t; i < n; i += THREADS) atomicAdd(&cnt[payS[off + i]], 1);  // LDS atomic
        __syncthreads();
        int node = k * 256 + t;
        if (node < N) {
            float dv = 1.0f / sqrtf(1.0f + (float)cnt[t]);
            disv[node] = dv;
            *(float*)(Hqr1 + (size_t)node * 128 + 64) = dv;
        }
    } else {
        // phase B: dst counting sort for bucket b-NB2
        int k = b - NB2;
        cnt[t] = 0;
        __syncthreads();
        int ecnt = gcurD[k], eoff = k * BCAP;
        for (int i = t; i < ecnt; i += THREADS)
            atomicAdd(&cnt[(payD[eoff + i] >> 22) & 255], 1);  // LDS atomic
        __syncthreads();
        int v = cnt[t];
        s[t] = v;
        __syncthreads();
        for (int d = 1; d < THREADS; d <<= 1) {
            int a = (t >= d) ? s[t - d] : 0;
            __syncthreads();
            s[t] += a;
            __syncthreads();
        }
        int excl = s[t] - v;
        int node = k * 256 + t;
        if (node < N) rc[node] = make_int2(eoff + excl, v);
        cur[t] = excl;
        __syncthreads();
        for (int i = t; i < ecnt; i += THREADS) {
            unsigned int u = payD[eoff + i];
            int p = atomicAdd(&cur[(u >> 22) & 255], 1);  // LDS atomic
            sorted[eoff + p] = u & 0x3FFFFFu;             // keep src | emb<<17
        }
    }
}

// ---- aggregate inner step: 8 lanes/node, 8 dims/lane. ONE random line per edge:
// q words + {dis,sc} live in the same 128-B record -> second access is an L1 hit.
__device__ __forceinline__ void edge_acc(unsigned int u, float dn,
                                         const unsigned char* __restrict__ Hqr, int c,
                                         const float (*embc)[64], float acc[8]) {
    int s0 = u & 0x1FFFF;
    int e0 = (u >> 17) & 31;
    const unsigned char* rec = Hqr + (size_t)s0 * 128;
    float2 ds = *(const float2*)(rec + 64);  // {dis, sc} — same line as q
    uint2 q = *(const uint2*)(rec + c);
    float w = ds.x * dn, ws = w * ds.y;
    float4 ea = *(const float4*)(&embc[e0][c]);
    float4 eb = *(const float4*)(&embc[e0][c + 4]);
    acc[0] = fmaf(ws, (float)sb(q.x, 0), fmaf(w, ea.x, acc[0]));
    acc[1] = fmaf(ws, (float)sb(q.x, 1), fmaf(w, ea.y, acc[1]));
    acc[2] = fmaf(ws, (float)sb(q.x, 2), fmaf(w, ea.z, acc[2]));
    acc[3] = fmaf(ws, (float)sb(q.x, 3), fmaf(w, ea.w, acc[3]));
    acc[4] = fmaf(ws, (float)sb(q.y, 0), fmaf(w, eb.x, acc[4]));
    acc[5] = fmaf(ws, (float)sb(q.y, 1), fmaf(w, eb.y, acc[5]));
    acc[6] = fmaf(ws, (float)sb(q.y, 2), fmaf(w, eb.z, acc[6]));
    acc[7] = fmaf(ws, (float)sb(q.y, 3), fmaf(w, eb.w, acc[7]));
}

// full per-node aggregate (4-wide, dual accumulators); returns o[8] for dims [c,c+8)
__device__ __forceinline__ void agg_node(int n, int c, const unsigned short* __restrict__ Hb,
                                         const unsigned char* __restrict__ Hqr,
                                         const float* __restrict__ disv,
                                         const int2* __restrict__ rc,
                                         const unsigned int* __restrict__ entries,
                                         const float (*ec)[64], float o[8]) {
    float dn = disv[n];
    uint4 hv = *(const uint4*)(Hb + (size_t)n * 64 + c);
    float4 ea = *(const float4*)(&ec[12][c]);  // self-loop: bt=4, bd=0 -> idx 12
    float4 eb = *(const float4*)(&ec[12][c + 4]);
    float nrm = dn * dn;
    float accA[8], accB[8];
    accA[0] = nrm * (bflo(hv.x) + ea.x);
    accA[1] = nrm * (bfhi(hv.x) + ea.y);
    accA[2] = nrm * (bflo(hv.y) + ea.z);
    accA[3] = nrm * (bfhi(hv.y) + ea.w);
    accA[4] = nrm * (bflo(hv.z) + eb.x);
    accA[5] = nrm * (bfhi(hv.z) + eb.y);
    accA[6] = nrm * (bflo(hv.w) + eb.z);
    accA[7] = nrm * (bfhi(hv.w) + eb.w);
#pragma unroll
    for (int j = 0; j < 8; ++j) accB[j] = 0.0f;

    int2 pc = rc[n];
    int p = pc.x;
    int end = p + pc.y;
    for (; p + 3 < end; p += 4) {
        unsigned int u0 = entries[p];
        unsigned int u1 = entries[p + 1];
        unsigned int u2 = entries[p + 2];
        unsigned int u3 = entries[p + 3];
        edge_acc(u0, dn, Hqr, c, ec, accA);
        edge_acc(u1, dn, Hqr, c, ec, accB);
        edge_acc(u2, dn, Hqr, c, ec, accA);
        edge_acc(u3, dn, Hqr, c, ec, accB);
    }
    for (; p < end; ++p) edge_acc(entries[p], dn, Hqr, c, ec, accA);
#pragma unroll
    for (int j = 0; j < 8; ++j) o[j] = accA[j] + accB[j];
}

// ---- K3 FUSED: aggregate layer 1 (ReLU, bf16) for 64 nodes -> LDS tile -> MFMA
// gemm2 -> Hb2/Hqr2 (record {dis,sc} written in epilogue).
__global__ __launch_bounds__(THREADS) void agg_gemm_kernel(
    const unsigned short* __restrict__ Hb1, const unsigned char* __restrict__ Hqr1,
    const float* __restrict__ disv, const float* __restrict__ ebond,
    const float* __restrict__ edir, const int2* __restrict__ rc,
    const unsigned int* __restrict__ entries, const float* __restrict__ W,
    const float* __restrict__ B, unsigned short* __restrict__ Hb2,
    unsigned char* __restrict__ Hqr2, int N) {
    __shared__ float embc[18][64];
    __shared__ __align__(16) unsigned short smA[64][72];  // bf16 A-tile, stride 72
    __shared__ __align__(16) float smC[64][68];           // epilogue staging
    int t = threadIdx.x;
    for (int i = t; i < 18 * 64; i += THREADS) {
        int row = i >> 6, c = i & 63;
        embc[row][c] = ebond[(row / 3) * 64 + c] + edir[(row % 3) * 64 + c];
    }
    __syncthreads();

    int tile = blockIdx.x;
    const float(*ec)[64] = (const float(*)[64])embc;
#pragma unroll 1
    for (int r = 0; r < 2; ++r) {
        int ln = r * 32 + (t >> 3);  // local row 0..63
        int n = tile * 64 + ln;
        int c = (t & 7) << 3;
        uint4 ov = make_uint4(0u, 0u, 0u, 0u);
        if (n < N) {
            float o[8];
            agg_node(n, c, Hb1, Hqr1, disv, rc, entries, ec, o);
            ov.x = (unsigned)f2bf(fmaxf(o[0], 0.0f)) | ((unsigned)f2bf(fmaxf(o[1], 0.0f)) << 16);
            ov.y = (unsigned)f2bf(fmaxf(o[2], 0.0f)) | ((unsigned)f2bf(fmaxf(o[3], 0.0f)) << 16);
            ov.z = (unsigned)f2bf(fmaxf(o[4], 0.0f)) | ((unsigned)f2bf(fmaxf(o[5], 0.0f)) << 16);
            ov.w = (unsigned)f2bf(fmaxf(o[6], 0.0f)) | ((unsigned)f2bf(fmaxf(o[7], 0.0f)) << 16);
        }
        *(uint4*)(&smA[ln][c]) = ov;  // (ln*72 + c)*2 bytes: 16B-aligned
    }
    __syncthreads();

    // gemm2 from the LDS A-tile
    int lane = t & 63;
    int wave = __builtin_amdgcn_readfirstlane(t >> 6);
    int l15 = lane & 15;
    int lk = lane >> 4;
    int lrow = wave * 16 + l15;
    bf16x8 a0 = *(const bf16x8*)(&smA[lrow][8 * lk]);
    bf16x8 a1 = *(const bf16x8*)(&smA[lrow][8 * lk + 32]);

    bf16x8 bfr[4][2];
    load_bfrags(W, l15, lk, bfr);

    f32x4 acc[4];
#pragma unroll
    for (int n = 0; n < 4; ++n) {
        f32x4 z = {0.0f, 0.0f, 0.0f, 0.0f};
        z = __builtin_amdgcn_mfma_f32_16x16x32_bf16(a0, bfr[n][0], z, 0, 0, 0);
        acc[n] = __builtin_amdgcn_mfma_f32_16x16x32_bf16(a1, bfr[n][1], z, 0, 0, 0);
    }
    gemm_epilogue(tile, acc, B, wave, l15, lk, t, Hb2, Hqr2, disv, N, smC);
}

// ---- K4: standalone aggregate (layer 2 -> fp32 out) ----
__global__ __launch_bounds__(THREADS) void aggregate_kernel(
    const unsigned short* __restrict__ Hb, const unsigned char* __restrict__ Hqr,
    const float* __restrict__ disv, const float* __restrict__ ebond,
    const float* __restrict__ edir, const int2* __restrict__ rc,
    const unsigned int* __restrict__ entries, float* __restrict__ out, int N) {
    __shared__ float embc[18][64];
    int t = threadIdx.x;
    for (int i = t; i < 18 * 64; i += THREADS) {
        int row = i >> 6, c = i & 63;
        embc[row][c] = ebond[(row / 3) * 64 + c] + edir[(row % 3) * 64 + c];
    }
    __syncthreads();

    int n = blockIdx.x * 32 + (t >> 3);
    if (n >= N) return;
    int c = (t & 7) << 3;
    float o[8];
    agg_node(n, c, Hb, Hqr, disv, rc, entries, (const float(*)[64])embc, o);
    *(float4*)(out + (size_t)n * 64 + c) = make_float4(o[0], o[1], o[2], o[3]);
    *(float4*)(out + (size_t)n * 64 + c + 4) = make_float4(o[4], o[5], o[6], o[7]);
}

extern "C" void kernel_launch(void* const* d_in, const int* in_sizes, int n_in,
                              void* d_out, int out_size, void* d_ws, size_t ws_size,
                              hipStream_t stream) {
    const float* x      = (const float*)d_in[0];
    const int*   eidx   = (const int*)d_in[1];
    const int*   eattr  = (const int*)d_in[2];
    const float* W1     = (const float*)d_in[3];
    const float* b1     = (const float*)d_in[4];
    const float* ebond1 = (const float*)d_in[5];
    const float* edir1  = (const float*)d_in[6];
    const float* W2     = (const float*)d_in[7];
    const float* b2     = (const float*)d_in[8];
    const float* ebond2 = (const float*)d_in[9];
    const float* edir2  = (const float*)d_in[10];

    const int N = in_sizes[0] / 64;
    const int E = in_sizes[1] / 2;
    const int* src = eidx;
    const int* dst = eidx + E;
    float* out = (float*)d_out;
    const int NB2 = (N + 255) >> 8;         // 256-node buckets
    const int SCB = (E + CHUNK - 1) / CHUNK;

    // Workspace (~73 MB of 256 MiB)
    char* w = (char*)d_ws;
    size_t Na = ((size_t)N * 4 + 255) & ~(size_t)255;
    size_t Nr = ((size_t)N * 128 + 255) & ~(size_t)255;  // 128-B records
    float* disv    = (float*)w;            w += Na;      // 1/sqrt(1+deg)
    int2*  rc      = (int2*)w;             w += 2 * Na;  // {row_ptr, cnt}
    int*   gcur    = (int*)w;              w += 2 * NBINS * 4;
    unsigned int* payD   = (unsigned int*)w;   w += (size_t)NBINS * BCAP * 4;   // 8 MB
    unsigned int* sorted = (unsigned int*)w;   w += (size_t)NBINS * BCAP * 4;   // 8 MB
    unsigned char* payS  = (unsigned char*)w;  w += (size_t)NBINS * BCAP;       // 2 MB
    unsigned short* Hb1  = (unsigned short*)w; w += (size_t)N * 64 * 2;         // 12.8 MB
    unsigned char*  Hqr1 = (unsigned char*)w;  w += Nr;                         // 12.8 MB
    unsigned short* Hb2  = (unsigned short*)w; w += (size_t)N * 64 * 2;         // 12.8 MB
    unsigned char*  Hqr2 = (unsigned char*)w;  w += Nr;                         // 12.8 MB
    int* gcurS = gcur;
    int* gcurD = gcur + NBINS;

    const int gT   = (N + 63) / 64;   // gemm/fused tiles
    const int gN32 = (N + 31) / 32;   // aggregate: 32 nodes/block

    // all gemm1 tiles ride in K0+K1 (gemm1 depends only on x; must be done before K3)
    const int t0 = min(gT, 512);
    const int t1 = gT - t0;

    zero_gemm_kernel<<<1 + t0, THREADS, 0, stream>>>(gcur, 2 * NBINS, x, W1, b1, Hb1, Hqr1,
                                                     N, 0);
    scatter_kernel<<<SCB + t1, THREADS, 0, stream>>>(src, dst, eattr, gcurS, gcurD, payS,
                                                     payD, E, SCB, x, W1, b1, Hb1, Hqr1,
                                                     N, t0);
    build_kernel<<<2 * NB2, THREADS, 0, stream>>>(payS, payD, gcurS, gcurD, sorted, rc,
                                                  disv, Hqr1, NB2, N);

    // fused: aggregate layer 1 (ReLU,bf16 in LDS) -> gemm2 -> Hb2/Hqr2
    agg_gemm_kernel<<<gT, THREADS, 0, stream>>>(Hb1, Hqr1, disv, ebond1, edir1, rc, sorted,
                                                W2, b2, Hb2, Hqr2, N);

    // layer 2 aggregate -> fp32 out
    aggregate_kernel<<<gN32, THREADS, 0, stream>>>(Hb2, Hqr2, disv, ebond2, edir2, rc,
                                                   sorted, out, N);
}

// Round 13
// 221.651 us; speedup vs baseline: 1.0409x; 1.0043x over previous
//
#include <hip/hip_runtime.h>

// GCN 2-layer forward (Hu et al. mol-GNN variant) — LDS-sorted coalesced scatter,
// bf16+int8 links, MFMA GEMM, fused agg1+gemm2. R13 = R10 layout + occupancy fixes.
//
//   dis[n] = 1/sqrt(1 + outdeg(n))
//   out[n] = dis[n]^2*(h_bf16[n]+emb_self) + sum_e dis[s]*dis[n]*(q8[s]*sc[s]+emb_e)
//
// Measured facts / ledger:
//  - R2: VALU GEMM 59us -> MFMA. R3: LDS-sorted coalesced scatter. R8 = 220.7 anchor.
//  - R10: fused agg1+gemm2 = 220.3; agg_gemm 51us (agg phase ~41us).
//  - R11 (coef-folded emb: VALU/conflict cut) and R12 (128-B record merge: request
//    cut) BOTH neutral-to-negative => gather is 128-B-SECTOR-bound: 1M compulsory
//    random sectors/layer ~= 128 MB at ~3.5 TB/s ~= 37us/layer. Aggregates are AT
//    that roofline (K4 @32 waves/CU == K3-agg @20 waves per-edge rate -> not
//    latency-elastic). Reverted to R10 layout.
//  - R13 (this): (a) all 1563 gemm1 riders in K0 @17.4KB LDS (9 blocks/CU) instead
//    of 1051 inside 37.9KB scatter (4 blocks/CU) — the R6 lesson; (b) K3 smA/smC
//    LDS union (31.2->22.0 KB, 5->7 blocks/CU). Numerics identical to R10.
// Payload: src(17b) | emb(5b)<<17 | dstLow8(8b)<<22 (30 bits).

#define THREADS 256
#define NBINS 512    // 256-node buckets, N <= 131072
#define BCAP 4096    // per-bucket edge capacity (mean 2560 @ E=1M,N=100k; sd~51)
#define CHUNK 2048   // edges per scatter block
#define GEMM_SMEM_BYTES (64 * 68 * 4)
// Wv[2048]u32 + SD[2048]u32 + DB[2048]u16 + SDB[2048]u16 + 6*512 ints + 256 ints
#define SC_SMEM (CHUNK * 4 * 2 + CHUNK * 2 * 2 + 6 * NBINS * 4 + 256 * 4)  // 37888

typedef __attribute__((ext_vector_type(8))) short bf16x8;
typedef __attribute__((ext_vector_type(4))) float f32x4;

__device__ __forceinline__ float bflo(unsigned int v) { return __uint_as_float(v << 16); }
__device__ __forceinline__ float bfhi(unsigned int v) { return __uint_as_float(v & 0xFFFF0000u); }
__device__ __forceinline__ unsigned short f2bf(float f) {  // round-to-nearest-even
    unsigned int u = __float_as_uint(f);
    return (unsigned short)((u + 0x7FFFu + ((u >> 16) & 1u)) >> 16);
}
__device__ __forceinline__ int sb(unsigned int w, int j) {  // signed byte j of word
    return (int)(w << (24 - 8 * j)) >> 24;
}

// ---- shared GEMM core pieces -------------------------------------------------
__device__ __forceinline__ void load_bfrags(const float* __restrict__ W, int l15, int lk,
                                            bf16x8 bfr[4][2]) {
#pragma unroll
    for (int n = 0; n < 4; ++n) {
        const float* wp = W + (size_t)(16 * n + l15) * 64 + 8 * lk;
#pragma unroll
        for (int ks = 0; ks < 2; ++ks) {
            float4 u0 = *(const float4*)(wp + 32 * ks);
            float4 u1 = *(const float4*)(wp + 32 * ks + 4);
            bf16x8 bb;
            bb[0] = (short)f2bf(u0.x); bb[1] = (short)f2bf(u0.y);
            bb[2] = (short)f2bf(u0.z); bb[3] = (short)f2bf(u0.w);
            bb[4] = (short)f2bf(u1.x); bb[5] = (short)f2bf(u1.y);
            bb[6] = (short)f2bf(u1.z); bb[7] = (short)f2bf(u1.w);
            bfr[n][ks] = bb;
        }
    }
}

// epilogue: bias+stage smC, then bf16 row + int8 quant row + scale writeout.
// dsc2 nonnull (fused layer-2): dsc2[grow] = {dsrc[grow].x, sc}; else dscy[grow].y = sc.
__device__ __forceinline__ void gemm_epilogue(int tile, f32x4 acc[4],
                                              const float* __restrict__ B, int wave,
                                              int l15, int lk, int t,
                                              unsigned short* __restrict__ Hb,
                                              unsigned char* __restrict__ Hq,
                                              float2* __restrict__ dscy,
                                              const float2* __restrict__ dsrc,
                                              float2* __restrict__ dsc2, int N,
                                              float (*smem)[68]) {
#pragma unroll
    for (int n = 0; n < 4; ++n) {
        float bv = B[16 * n + l15];
        int col = 16 * n + l15;
#pragma unroll
        for (int r = 0; r < 4; ++r)
            smem[16 * wave + 4 * lk + r][col] = acc[n][r] + bv;
    }
    __syncthreads();

#pragma unroll
    for (int i = 0; i < 2; ++i) {
        int idx = t + i * THREADS;
        int r = idx >> 3;
        int c8 = (idx & 7) << 3;
        int grow = tile * 64 + r;
        float4 va = *(const float4*)(&smem[r][c8]);
        float4 vb = *(const float4*)(&smem[r][c8 + 4]);
        float v[8] = {va.x, va.y, va.z, va.w, vb.x, vb.y, vb.z, vb.w};
        float m = fabsf(v[0]);
#pragma unroll
        for (int j = 1; j < 8; ++j) m = fmaxf(m, fabsf(v[j]));
        m = fmaxf(m, __shfl_xor(m, 1));  // 8 lanes/row are contiguous
        m = fmaxf(m, __shfl_xor(m, 2));
        m = fmaxf(m, __shfl_xor(m, 4));
        if (grow < N) {
            uint4 o;
            o.x = (unsigned)f2bf(v[0]) | ((unsigned)f2bf(v[1]) << 16);
            o.y = (unsigned)f2bf(v[2]) | ((unsigned)f2bf(v[3]) << 16);
            o.z = (unsigned)f2bf(v[4]) | ((unsigned)f2bf(v[5]) << 16);
            o.w = (unsigned)f2bf(v[6]) | ((unsigned)f2bf(v[7]) << 16);
            *(uint4*)(Hb + (size_t)grow * 64 + c8) = o;
            float inv = m > 0.0f ? 127.0f / m : 0.0f;
            int q[8];
#pragma unroll
            for (int j = 0; j < 8; ++j) q[j] = __float2int_rn(v[j] * inv);
            uint2 qp;
            qp.x = (unsigned)(q[0] & 255) | ((unsigned)(q[1] & 255) << 8) |
                   ((unsigned)(q[2] & 255) << 16) | ((unsigned)(q[3] & 255) << 24);
            qp.y = (unsigned)(q[4] & 255) | ((unsigned)(q[5] & 255) << 8) |
                   ((unsigned)(q[6] & 255) << 16) | ((unsigned)(q[7] & 255) << 24);
            *(uint2*)(Hq + (size_t)grow * 64 + c8) = qp;
            if ((idx & 7) == 0) {
                float sc = m * (1.0f / 127.0f);
                if (dsc2) dsc2[grow] = make_float2(dsrc[grow].x, sc);
                else dscy[grow].y = sc;
            }
        }
    }
}

// ---- GEMM tile body (MFMA), A from global fp32 (layer 1) ----
__device__ __forceinline__ void gemm64_body(int tile, const float* __restrict__ Xv,
                                            const float* __restrict__ W,
                                            const float* __restrict__ B,
                                            unsigned short* __restrict__ Hb,
                                            unsigned char* __restrict__ Hq,
                                            float2* __restrict__ dsc, int N,
                                            float (*smem)[68]) {
    int t = threadIdx.x;
    int lane = t & 63;
    int wave = __builtin_amdgcn_readfirstlane(t >> 6);
    int l15 = lane & 15;
    int lk = lane >> 4;  // k-chunk id 0..3
    int arow = tile * 64 + wave * 16 + l15;

    bf16x8 a0, a1;
    if (arow < N) {
        const float* xp = Xv + (size_t)arow * 64 + 8 * lk;
        float4 v0 = *(const float4*)xp;
        float4 v1 = *(const float4*)(xp + 4);
        float4 v2 = *(const float4*)(xp + 32);
        float4 v3 = *(const float4*)(xp + 36);
        a0[0] = (short)f2bf(v0.x); a0[1] = (short)f2bf(v0.y);
        a0[2] = (short)f2bf(v0.z); a0[3] = (short)f2bf(v0.w);
        a0[4] = (short)f2bf(v1.x); a0[5] = (short)f2bf(v1.y);
        a0[6] = (short)f2bf(v1.z); a0[7] = (short)f2bf(v1.w);
        a1[0] = (short)f2bf(v2.x); a1[1] = (short)f2bf(v2.y);
        a1[2] = (short)f2bf(v2.z); a1[3] = (short)f2bf(v2.w);
        a1[4] = (short)f2bf(v3.x); a1[5] = (short)f2bf(v3.y);
        a1[6] = (short)f2bf(v3.z); a1[7] = (short)f2bf(v3.w);
    } else {
#pragma unroll
        for (int e = 0; e < 8; ++e) { a0[e] = 0; a1[e] = 0; }
    }

    bf16x8 bfr[4][2];
    load_bfrags(W, l15, lk, bfr);

    f32x4 acc[4];
#pragma unroll
    for (int n = 0; n < 4; ++n) {
        f32x4 z = {0.0f, 0.0f, 0.0f, 0.0f};
        z = __builtin_amdgcn_mfma_f32_16x16x32_bf16(a0, bfr[n][0], z, 0, 0, 0);
        acc[n] = __builtin_amdgcn_mfma_f32_16x16x32_bf16(a1, bfr[n][1], z, 0, 0, 0);
    }
    gemm_epilogue(tile, acc, B, wave, l15, lk, t, Hb, Hq, dsc, nullptr, nullptr, N, smem);
}

// ---- K0: zero cursors (block 0) + ALL gemm1 tiles (blocks 1..gT) @17.4KB LDS ----
__global__ __launch_bounds__(THREADS) void zero_gemm_kernel(
    int* __restrict__ gcur, int ncur, const float* __restrict__ X,
    const float* __restrict__ W1, const float* __restrict__ B1,
    unsigned short* __restrict__ Hb, unsigned char* __restrict__ Hq,
    float2* __restrict__ dsc, int N) {
    __shared__ __align__(16) char sh[GEMM_SMEM_BYTES];
    int b = blockIdx.x;
    if (b == 0) {
        for (int i = threadIdx.x; i < ncur; i += THREADS) gcur[i] = 0;
        return;
    }
    gemm64_body(b - 1, X, W1, B1, Hb, Hq, dsc, N, (float(*)[68])sh);
}

// ---- K1: pure LDS-sorted scatter into 512 bins (no riders -> no LDS inheritance) ----
__global__ __launch_bounds__(THREADS) void scatter_kernel(
    const int* __restrict__ src, const int* __restrict__ dst, const int* __restrict__ attr,
    int* __restrict__ gcurS, int* __restrict__ gcurD, unsigned char* __restrict__ payS,
    unsigned int* __restrict__ payD, int E) {
    __shared__ __align__(16) char sh[SC_SMEM];
    int b = blockIdx.x;
    unsigned int* Wv = (unsigned int*)sh;                 // [CHUNK]
    unsigned int* SD = Wv + CHUNK;                        // [CHUNK] dst-sorted words
    unsigned short* DB = (unsigned short*)(SD + CHUNK);   // [CHUNK] dst bin
    unsigned short* SDB = DB + CHUNK;                     // [CHUNK] sorted dst bin
    int* hD = (int*)(SDB + CHUNK);
    int* hS = hD + NBINS;
    int* mapD = hS + NBINS;
    int* mapS = mapD + NBINS;
    int* curD = mapS + NBINS;
    int* curS = curD + NBINS;
    int* scn = curS + NBINS;                              // [256]
    unsigned char* SS = (unsigned char*)Wv;               // reuse after place-D
    unsigned short* SSB = DB;                             // reuse after place-D

    int t = threadIdx.x;
    for (int k = t; k < NBINS; k += THREADS) { hD[k] = 0; hS[k] = 0; }
    __syncthreads();

    int lo = b * CHUNK, hi = min(E, lo + CHUNK);
    int nch = hi - lo;
    const int2* ap = (const int2*)attr;
    for (int li = t; li < nch; li += THREADS) {
        int i = lo + li;
        int sv = src[i], dv = dst[i];
        int2 a = ap[i];
        Wv[li] = (unsigned int)sv | ((unsigned int)(a.x * 3 + a.y) << 17) |
                 ((unsigned int)(dv & 255) << 22);
        DB[li] = (unsigned short)(dv >> 8);
        atomicAdd(&hD[dv >> 8], 1);  // LDS atomic
        atomicAdd(&hS[sv >> 8], 1);  // LDS atomic
    }
    __syncthreads();

    // reserve global ranges (one atomic per touched bin per stream)
    for (int k = t; k < NBINS; k += THREADS) {
        int h = hD[k];
        int r = h ? atomicAdd(&gcurD[k], h) : 0;  // global atomic, low contention
        mapD[k] = k * BCAP + r;
        int h2 = hS[k];
        int r2 = h2 ? atomicAdd(&gcurS[k], h2) : 0;
        mapS[k] = k * BCAP + r2;
    }
    __syncthreads();

    // exclusive scan of hD over 512 bins (2 bins/thread) -> curD (local start), map adj
    scn[t] = hD[2 * t] + hD[2 * t + 1];
    __syncthreads();
    for (int d = 1; d < THREADS; d <<= 1) {
        int a = (t >= d) ? scn[t - d] : 0;
        __syncthreads();
        scn[t] += a;
        __syncthreads();
    }
    {
        int off = t ? scn[t - 1] : 0;
        curD[2 * t] = off;
        curD[2 * t + 1] = off + hD[2 * t];
        mapD[2 * t] -= off;
        mapD[2 * t + 1] -= off + hD[2 * t];
    }
    __syncthreads();
    // same for hS
    scn[t] = hS[2 * t] + hS[2 * t + 1];
    __syncthreads();
    for (int d = 1; d < THREADS; d <<= 1) {
        int a = (t >= d) ? scn[t - d] : 0;
        __syncthreads();
        scn[t] += a;
        __syncthreads();
    }
    {
        int off = t ? scn[t - 1] : 0;
        curS[2 * t] = off;
        curS[2 * t + 1] = off + hS[2 * t];
        mapS[2 * t] -= off;
        mapS[2 * t + 1] -= off + hS[2 * t];
    }
    __syncthreads();

    // place by dst-bin (consumes Wv/DB into SD/SDB)
    for (int li = t; li < nch; li += THREADS) {
        int k = DB[li];
        int p = atomicAdd(&curD[k], 1);  // LDS atomic
        SD[p] = Wv[li];
        SDB[p] = (unsigned short)k;
    }
    __syncthreads();

    // place by src-bin (sources from SD; reuses Wv region as SS, DB as SSB)
    for (int li = t; li < nch; li += THREADS) {
        int val = (int)(SD[li] & 0x1FFFFu);
        int k = val >> 8;
        int p = atomicAdd(&curS[k], 1);  // LDS atomic
        SS[p] = (unsigned char)(val & 255);
        SSB[p] = (unsigned short)k;
    }
    __syncthreads();

    // linear coalesced writeout
    for (int li = t; li < nch; li += THREADS) {
        payD[mapD[SDB[li]] + li] = SD[li];
        payS[mapS[SSB[li]] + li] = SS[li];
    }
}

// ---- K2: non-redundant build at 256-node buckets. Blocks [0,NB2): out-degree
// histogram -> dsc.x. Blocks [NB2,2*NB2): 256-bin counting sort -> sorted + rc.
__global__ __launch_bounds__(THREADS) void build_kernel(
    const unsigned char* __restrict__ payS, const unsigned int* __restrict__ payD,
    const int* __restrict__ gcurS, const int* __restrict__ gcurD,
    unsigned int* __restrict__ sorted, int2* __restrict__ rc,
    int NB2, float2* __restrict__ dsc, int N) {
    __shared__ int cnt[256];
    __shared__ int cur[256];
    __shared__ int s[THREADS];
    int t = threadIdx.x;
    int b = blockIdx.x;
    if (b < NB2) {
        // phase A: out-degree for bucket b
        int k = b;
        cnt[t] = 0;
        __syncthreads();
        int n = gcurS[k], off = k * BCAP;
        for (int i = t; i < n; i += THREADS) atomicAdd(&cnt[payS[off + i]], 1);  // LDS atomic
        __syncthreads();
        int node = k * 256 + t;
        if (node < N) dsc[node].x = 1.0f / sqrtf(1.0f + (float)cnt[t]);
    } else {
        // phase B: dst counting sort for bucket b-NB2
        int k = b - NB2;
        cnt[t] = 0;
        __syncthreads();
        int ecnt = gcurD[k], eoff = k * BCAP;
        for (int i = t; i < ecnt; i += THREADS)
            atomicAdd(&cnt[(payD[eoff + i] >> 22) & 255], 1);  // LDS atomic
        __syncthreads();
        int v = cnt[t];
        s[t] = v;
        __syncthreads();
        for (int d = 1; d < THREADS; d <<= 1) {
            int a = (t >= d) ? s[t - d] : 0;
            __syncthreads();
            s[t] += a;
            __syncthreads();
        }
        int excl = s[t] - v;
        int node = k * 256 + t;
        if (node < N) rc[node] = make_int2(eoff + excl, v);
        cur[t] = excl;
        __syncthreads();
        for (int i = t; i < ecnt; i += THREADS) {
            unsigned int u = payD[eoff + i];
            int p = atomicAdd(&cur[(u >> 22) & 255], 1);  // LDS atomic
            sorted[eoff + p] = u & 0x3FFFFFu;             // keep src | emb<<17
        }
    }
}

// ---- aggregate inner step: 8 lanes/node, 8 dims/lane ----
__device__ __forceinline__ void edge_acc(unsigned int u, float dn,
                                         const float2* __restrict__ dsc,
                                         const unsigned char* __restrict__ Hq, int c,
                                         const float (*embc)[64], float acc[8]) {
    int s0 = u & 0x1FFFF;
    int e0 = (u >> 17) & 31;
    float2 ds = dsc[s0];
    uint2 q = *(const uint2*)(Hq + (size_t)s0 * 64 + c);
    float w = ds.x * dn, ws = w * ds.y;
    float4 ea = *(const float4*)(&embc[e0][c]);
    float4 eb = *(const float4*)(&embc[e0][c + 4]);
    acc[0] = fmaf(ws, (float)sb(q.x, 0), fmaf(w, ea.x, acc[0]));
    acc[1] = fmaf(ws, (float)sb(q.x, 1), fmaf(w, ea.y, acc[1]));
    acc[2] = fmaf(ws, (float)sb(q.x, 2), fmaf(w, ea.z, acc[2]));
    acc[3] = fmaf(ws, (float)sb(q.x, 3), fmaf(w, ea.w, acc[3]));
    acc[4] = fmaf(ws, (float)sb(q.y, 0), fmaf(w, eb.x, acc[4]));
    acc[5] = fmaf(ws, (float)sb(q.y, 1), fmaf(w, eb.y, acc[5]));
    acc[6] = fmaf(ws, (float)sb(q.y, 2), fmaf(w, eb.z, acc[6]));
    acc[7] = fmaf(ws, (float)sb(q.y, 3), fmaf(w, eb.w, acc[7]));
}

// full per-node aggregate (4-wide, dual accumulators); returns o[8] for dims [c,c+8)
__device__ __forceinline__ void agg_node(int n, int c, const unsigned short* __restrict__ Hb,
                                         const unsigned char* __restrict__ Hq,
                                         const float2* __restrict__ dsc,
                                         const int2* __restrict__ rc,
                                         const unsigned int* __restrict__ entries,
                                         const float (*ec)[64], float o[8]) {
    float dn = dsc[n].x;
    uint4 hv = *(const uint4*)(Hb + (size_t)n * 64 + c);
    float4 ea = *(const float4*)(&ec[12][c]);  // self-loop: bt=4, bd=0 -> idx 12
    float4 eb = *(const float4*)(&ec[12][c + 4]);
    float nrm = dn * dn;
    float accA[8], accB[8];
    accA[0] = nrm * (bflo(hv.x) + ea.x);
    accA[1] = nrm * (bfhi(hv.x) + ea.y);
    accA[2] = nrm * (bflo(hv.y) + ea.z);
    accA[3] = nrm * (bfhi(hv.y) + ea.w);
    accA[4] = nrm * (bflo(hv.z) + eb.x);
    accA[5] = nrm * (bfhi(hv.z) + eb.y);
    accA[6] = nrm * (bflo(hv.w) + eb.z);
    accA[7] = nrm * (bfhi(hv.w) + eb.w);
#pragma unroll
    for (int j = 0; j < 8; ++j) accB[j] = 0.0f;

    int2 pc = rc[n];
    int p = pc.x;
    int end = p + pc.y;
    for (; p + 3 < end; p += 4) {
        unsigned int u0 = entries[p];
        unsigned int u1 = entries[p + 1];
        unsigned int u2 = entries[p + 2];
        unsigned int u3 = entries[p + 3];
        edge_acc(u0, dn, dsc, Hq, c, ec, accA);
        edge_acc(u1, dn, dsc, Hq, c, ec, accB);
        edge_acc(u2, dn, dsc, Hq, c, ec, accA);
        edge_acc(u3, dn, dsc, Hq, c, ec, accB);
    }
    for (; p < end; ++p) edge_acc(entries[p], dn, dsc, Hq, c, ec, accA);
#pragma unroll
    for (int j = 0; j < 8; ++j) o[j] = accA[j] + accB[j];
}

// ---- K3 FUSED: aggregate layer 1 (ReLU, bf16) -> LDS tile -> MFMA gemm2.
// smA (9.2KB) and smC (17.4KB) UNIONED: 31.2 -> 22.0 KB LDS, 5 -> 7 blocks/CU.
__global__ __launch_bounds__(THREADS) void agg_gemm_kernel(
    const unsigned short* __restrict__ Hb1, const unsigned char* __restrict__ Hq1,
    const float2* __restrict__ dsc, const float* __restrict__ ebond,
    const float* __restrict__ edir, const int2* __restrict__ rc,
    const unsigned int* __restrict__ entries, const float* __restrict__ W,
    const float* __restrict__ B, unsigned short* __restrict__ Hb2,
    unsigned char* __restrict__ Hq2, float2* __restrict__ dsc2, int N) {
    __shared__ float embc[18][64];
    __shared__ __align__(16) char smU[64 * 68 * 4];       // union: A-tile then C staging
    unsigned short (*smA)[72] = (unsigned short(*)[72])smU;  // 64*72*2 = 9216 <= 17408
    float (*smC)[68] = (float(*)[68])smU;
    int t = threadIdx.x;
    for (int i = t; i < 18 * 64; i += THREADS) {
        int row = i >> 6, c = i & 63;
        embc[row][c] = ebond[(row / 3) * 64 + c] + edir[(row % 3) * 64 + c];
    }
    __syncthreads();

    int tile = blockIdx.x;
    const float(*ec)[64] = (const float(*)[64])embc;
#pragma unroll 1
    for (int r = 0; r < 2; ++r) {
        int ln = r * 32 + (t >> 3);  // local row 0..63
        int n = tile * 64 + ln;
        int c = (t & 7) << 3;
        uint4 ov = make_uint4(0u, 0u, 0u, 0u);
        if (n < N) {
            float o[8];
            agg_node(n, c, Hb1, Hq1, dsc, rc, entries, ec, o);
            ov.x = (unsigned)f2bf(fmaxf(o[0], 0.0f)) | ((unsigned)f2bf(fmaxf(o[1], 0.0f)) << 16);
            ov.y = (unsigned)f2bf(fmaxf(o[2], 0.0f)) | ((unsigned)f2bf(fmaxf(o[3], 0.0f)) << 16);
            ov.z = (unsigned)f2bf(fmaxf(o[4], 0.0f)) | ((unsigned)f2bf(fmaxf(o[5], 0.0f)) << 16);
            ov.w = (unsigned)f2bf(fmaxf(o[6], 0.0f)) | ((unsigned)f2bf(fmaxf(o[7], 0.0f)) << 16);
        }
        *(uint4*)(&smA[ln][c]) = ov;  // (ln*72 + c)*2 bytes: 16B-aligned
    }
    __syncthreads();

    // gemm2: read A-fragments from the union, then barrier before epilogue reuses it
    int lane = t & 63;
    int wave = __builtin_amdgcn_readfirstlane(t >> 6);
    int l15 = lane & 15;
    int lk = lane >> 4;
    int lrow = wave * 16 + l15;
    bf16x8 a0 = *(const bf16x8*)(&smA[lrow][8 * lk]);
    bf16x8 a1 = *(const bf16x8*)(&smA[lrow][8 * lk + 32]);
    __syncthreads();  // all smA reads complete before smC overwrites the union

    bf16x8 bfr[4][2];
    load_bfrags(W, l15, lk, bfr);

    f32x4 acc[4];
#pragma unroll
    for (int n = 0; n < 4; ++n) {
        f32x4 z = {0.0f, 0.0f, 0.0f, 0.0f};
        z = __builtin_amdgcn_mfma_f32_16x16x32_bf16(a0, bfr[n][0], z, 0, 0, 0);
        acc[n] = __builtin_amdgcn_mfma_f32_16x16x32_bf16(a1, bfr[n][1], z, 0, 0, 0);
    }
    gemm_epilogue(tile, acc, B, wave, l15, lk, t, Hb2, Hq2, nullptr, dsc, dsc2, N, smC);
}

// ---- K4: standalone aggregate (layer 2 -> fp32 out) ----
__global__ __launch_bounds__(THREADS) void aggregate_kernel(
    const unsigned short* __restrict__ Hb, const unsigned char* __restrict__ Hq,
    const float2* __restrict__ dsc, const float* __restrict__ ebond,
    const float* __restrict__ edir, const int2* __restrict__ rc,
    const unsigned int* __restrict__ entries, float* __restrict__ out, int N) {
    __shared__ float embc[18][64];
    int t = threadIdx.x;
    for (int i = t; i < 18 * 64; i += THREADS) {
        int row = i >> 6, c = i & 63;
        embc[row][c] = ebond[(row / 3) * 64 + c] + edir[(row % 3) * 64 + c];
    }
    __syncthreads();

    int n = blockIdx.x * 32 + (t >> 3);
    if (n >= N) return;
    int c = (t & 7) << 3;
    float o[8];
    agg_node(n, c, Hb, Hq, dsc, rc, entries, (const float(*)[64])embc, o);
    *(float4*)(out + (size_t)n * 64 + c) = make_float4(o[0], o[1], o[2], o[3]);
    *(float4*)(out + (size_t)n * 64 + c + 4) = make_float4(o[4], o[5], o[6], o[7]);
}

extern "C" void kernel_launch(void* const* d_in, const int* in_sizes, int n_in,
                              void* d_out, int out_size, void* d_ws, size_t ws_size,
                              hipStream_t stream) {
    const float* x      = (const float*)d_in[0];
    const int*   eidx   = (const int*)d_in[1];
    const int*   eattr  = (const int*)d_in[2];
    const float* W1     = (const float*)d_in[3];
    const float* b1     = (const float*)d_in[4];
    const float* ebond1 = (const float*)d_in[5];
    const float* edir1  = (const float*)d_in[6];
    const float* W2     = (const float*)d_in[7];
    const float* b2     = (const float*)d_in[8];
    const float* ebond2 = (const float*)d_in[9];
    const float* edir2  = (const float*)d_in[10];

    const int N = in_sizes[0] / 64;
    const int E = in_sizes[1] / 2;
    const int* src = eidx;
    const int* dst = eidx + E;
    float* out = (float*)d_out;
    const int NB2 = (N + 255) >> 8;         // 256-node buckets
    const int SCB = (E + CHUNK - 1) / CHUNK;

    // Workspace (~60 MB of 256 MiB)
    char* w = (char*)d_ws;
    size_t Na = ((size_t)N * 4 + 255) & ~(size_t)255;
    float2* dsc    = (float2*)w;           w += 2 * Na;   // layer1 {dis, scale1}
    float2* dsc2   = (float2*)w;           w += 2 * Na;   // layer2 {dis, scale2}
    int2*  rc      = (int2*)w;             w += 2 * Na;   // {row_ptr, cnt}
    int*   gcur    = (int*)w;              w += 2 * NBINS * 4;
    unsigned int* payD   = (unsigned int*)w;   w += (size_t)NBINS * BCAP * 4;   // 8 MB
    unsigned int* sorted = (unsigned int*)w;   w += (size_t)NBINS * BCAP * 4;   // 8 MB
    unsigned char* payS  = (unsigned char*)w;  w += (size_t)NBINS * BCAP;       // 2 MB
    unsigned short* Hb1  = (unsigned short*)w; w += (size_t)N * 64 * 2;         // 12.8 MB
    unsigned char*  Hq1  = (unsigned char*)w;  w += ((size_t)N * 64 + 255) & ~(size_t)255;
    unsigned short* Hb2  = (unsigned short*)w; w += (size_t)N * 64 * 2;         // 12.8 MB
    unsigned char*  Hq2  = (unsigned char*)w;  w += ((size_t)N * 64 + 255) & ~(size_t)255;
    int* gcurS = gcur;
    int* gcurD = gcur + NBINS;

    const int gT   = (N + 63) / 64;   // gemm/fused tiles
    const int gN32 = (N + 31) / 32;   // aggregate: 32 nodes/block

    zero_gemm_kernel<<<1 + gT, THREADS, 0, stream>>>(gcur, 2 * NBINS, x, W1, b1, Hb1, Hq1,
                                                     dsc, N);
    scatter_kernel<<<SCB, THREADS, 0, stream>>>(src, dst, eattr, gcurS, gcurD, payS,
                                                payD, E);
    build_kernel<<<2 * NB2, THREADS, 0, stream>>>(payS, payD, gcurS, gcurD, sorted,
                                                  rc, NB2, dsc, N);

    // fused: aggregate layer 1 (ReLU,bf16 in LDS) -> gemm2 -> Hb2/Hq2/dsc2
    agg_gemm_kernel<<<gT, THREADS, 0, stream>>>(Hb1, Hq1, dsc, ebond1, edir1, rc, sorted,
                                                W2, b2, Hb2, Hq2, dsc2, N);

    // layer 2 aggregate -> fp32 out
    aggregate_kernel<<<gN32, THREADS, 0, stream>>>(Hb2, Hq2, dsc2, ebond2, edir2, rc,
                                                   sorted, out, N);
}